// Round 1
// baseline (651.346 us; speedup 1.0000x reference)
//
#include <hip/hip_runtime.h>
#include <stdint.h>

#define DI __device__ __forceinline__

typedef __attribute__((ext_vector_type(8))) __bf16 bf16x8;
typedef __attribute__((ext_vector_type(8))) unsigned short u16x8;
typedef __attribute__((ext_vector_type(4))) float f32x4;
typedef __attribute__((ext_vector_type(4))) uint32_t u32x4;
typedef unsigned short u16;

constexpr int Bb = 4, Cc = 256, Ss = 4096, HD = 64;
constexpr int ELEMS = Bb * Cc * Ss;  // 4194304

DI float bf2f(u16 h) { union { unsigned u; float f; } x; x.u = ((unsigned)h) << 16; return x.f; }
DI u16 f2bf(float f) {
  union { float f; unsigned u; } x; x.f = f;
  return (u16)((x.u + 0x7FFFu + ((x.u >> 16) & 1u)) >> 16);
}
DI uint32_t pack2bf_trunc(float a, float b) {  // low16=bf(a), high16=bf(b), truncating
  union { float f; uint32_t u; } xa, xb;
  xa.f = a; xb.f = b;
  return __builtin_amdgcn_perm(xb.u, xa.u, 0x07060302u);
}
DI bf16x8 ldfrag(const u16* p) { return __builtin_bit_cast(bf16x8, *(const u16x8*)p); }

// ---------------- kernel 0: x (B,C,S) fp32 -> xt (B,S,C) bf16; + weight conversion fused ----------------
// LDS uses XOR column-block swizzle: element (r,c) lives at T[r][((c>>3)^((r>>3)&7))*8 + (c&7)].
// Write: vector u16x8, ~2-way banks. Read: scalar, all-32-banks distinct (was 16-way conflicted).
__global__ __launch_bounds__(256) void k_transpose(const float* __restrict__ x, u16* __restrict__ xt,
                                                   const float* __restrict__ wq, const float* __restrict__ wo,
                                                   u16* __restrict__ wqb, u16* __restrict__ wob) {
  __shared__ u16 T[64][72];
  const int st = blockIdx.x, ct = blockIdx.y, b = blockIdx.z;
  const int tid = threadIdx.x;
  // fused weight conversion: 1024 blocks x 256 threads == 262144 == 196608 + 65536
  {
    int flat = blockIdx.x + 64 * blockIdx.y + 256 * blockIdx.z;
    int widx = flat * 256 + tid;
    if (widx < 196608) wqb[widx] = f2bf(wq[widx]);
    else wob[widx - 196608] = f2bf(wo[widx - 196608]);
  }
#pragma unroll
  for (int e = 0; e < 2; e++) {
    int ss = tid + e * 256;
    int r = ss >> 3, seg = ss & 7;
    size_t base = ((size_t)(b * Cc + ct * 64 + r) << 12) + st * 64 + seg * 8;
    u16x8 t;
#pragma unroll
    for (int j = 0; j < 8; j++) t[j] = f2bf(x[base + j]);
    *(u16x8*)&T[r][(seg ^ ((r >> 3) & 7)) * 8] = t;
  }
  __syncthreads();
#pragma unroll
  for (int e = 0; e < 2; e++) {
    int ss = tid + e * 256;
    int sr = ss >> 3, cseg = ss & 7;
    u16x8 o;
#pragma unroll
    for (int j = 0; j < 8; j++) {
      int row = cseg * 8 + j;
      o[j] = T[row][(((sr >> 3) ^ cseg) * 8) + (sr & 7)];
    }
    *(u16x8*)(xt + ((size_t)(b * Ss + st * 64 + sr) << 8) + ct * 64 + cseg * 8) = o;
  }
}

// ---- shared GEMM staging: rows [r0,r0+128) x cols [k0,k0+32), pitch-40 LDS ----
DI void stage_tile(const u16* __restrict__ src, int pitch, int r0, int k0, u16 (*dst)[40], int tid) {
#pragma unroll
  for (int e = 0; e < 2; e++) {
    int c = tid + e * 256;
    int row = c >> 2, seg = c & 3;
    u16x8 t = *(const u16x8*)(src + (size_t)(r0 + row) * pitch + k0 + seg * 8);
    *(u16x8*)&dst[row][seg * 8] = t;
  }
}

// ---------------- kernel 1: qkv GEMM.  q:[bh][s][64]*(0.125*log2e)  k,v:[bh][s][64] ----------------
__global__ __launch_bounds__(256) void k_qkv(const u16* __restrict__ xt, const u16* __restrict__ w,
                                             const float* __restrict__ bias,
                                             u16* __restrict__ q, u16* __restrict__ kk_, u16* __restrict__ vv_) {
  __shared__ u16 As[128][40], Bs[128][40];
  const int tid = threadIdx.x;
  const int wv = tid >> 6, lane = tid & 63;
  const int wm = wv >> 1, wn = wv & 1;
  const int lr = lane & 15, quad = lane >> 4;
  const int r0 = blockIdx.x * 128;
  const int j0 = blockIdx.y * 128;
  f32x4 acc[4][4] = {};
  for (int k0 = 0; k0 < 256; k0 += 32) {
    __syncthreads();
    stage_tile(xt, 256, r0, k0, As, tid);
    stage_tile(w, 256, j0, k0, Bs, tid);
    __syncthreads();
    bf16x8 a[4], b[4];
#pragma unroll
    for (int mt = 0; mt < 4; mt++) a[mt] = ldfrag(&As[wm * 64 + mt * 16 + lr][quad * 8]);
#pragma unroll
    for (int nt = 0; nt < 4; nt++) b[nt] = ldfrag(&Bs[wn * 64 + nt * 16 + lr][quad * 8]);
#pragma unroll
    for (int mt = 0; mt < 4; mt++)
#pragma unroll
      for (int nt = 0; nt < 4; nt++)
        acc[mt][nt] = __builtin_amdgcn_mfma_f32_16x16x32_bf16(a[mt], b[nt], acc[mt][nt], 0, 0, 0);
  }
#pragma unroll
  for (int nt = 0; nt < 4; nt++) {
    int j = j0 + wn * 64 + nt * 16 + lr;
    float bj = bias[j];
    int part = j >> 8, cc = j & 255, head = cc >> 6, d = cc & 63;
    u16* outp = (part == 0) ? q : (part == 1) ? kk_ : vv_;
    float sc = (part == 0) ? 0.18033688f : 1.0f;  // 0.125*log2(e), exp2-domain scores
#pragma unroll
    for (int mt = 0; mt < 4; mt++)
#pragma unroll
      for (int rg = 0; rg < 4; rg++) {
        int row = r0 + wm * 64 + mt * 16 + quad * 4 + rg;
        int b_ = row >> 12, s = row & 4095;
        outp[((size_t)((b_ * 4 + head) * Ss + s) << 6) + d] = f2bf((acc[mt][nt][rg] + bj) * sc);
      }
  }
}

// ---------------- v [bh][s][64] -> vt [bh][d][chunk*64 + slot] (key-permuted transpose) ----------------
// Same XOR swizzle on the LDS tile to break read conflicts.
__global__ __launch_bounds__(256) void k_vt(const u16* __restrict__ v, u16* __restrict__ vt) {
  __shared__ u16 T[64][72];
  const int chunk = blockIdx.x, bh = blockIdx.y;
  const int tid = threadIdx.x;
#pragma unroll
  for (int e = 0; e < 2; e++) {
    int row = (tid >> 3) + e * 32, seg = tid & 7;
    *(u16x8*)&T[row][(seg ^ ((row >> 3) & 7)) * 8] =
        *(const u16x8*)(v + ((size_t)(bh * Ss + chunk * 64 + row) << 6) + seg * 8);
  }
  __syncthreads();
#pragma unroll
  for (int e = 0; e < 2; e++) {
    int d = (tid >> 3) + e * 32, seg = tid & 7;
    u16x8 o;
#pragma unroll
    for (int j = 0; j < 8; j++) {
      int slot = seg * 8 + j;
      int t = (((slot >> 5) & 1) << 1) | ((slot >> 2) & 1);
      int w6 = t * 16 + (((slot >> 3) & 3) << 2) + (slot & 3);
      o[j] = T[w6][(((d >> 3) ^ ((w6 >> 3) & 7)) * 8) + (d & 7)];
    }
    *(u16x8*)(vt + ((size_t)(bh * 64 + d) << 12) + chunk * 64 + seg * 8) = o;
  }
}

// ---------------- kernel 2: flash attention, S^T form, exp2 no-max softmax ----------------
// 64 q/wave, 256 q-rows/block, double-buffered staging with early stores, l via ones-MFMA.
// K-split: each split writes NORMALIZED bf16 partials + l; combine is an l-weighted average.
// LDS tiles [64][64] with 16B-granule XOR swizzle (g ^= row&7): conflict-free reads AND writes,
// 32KB/block -> 4 blocks/CU at grid 1024 (nsplit=4).
__global__ __launch_bounds__(256, 4) void k_attn(const u16* __restrict__ Q, const u16* __restrict__ K,
                                                 const u16* __restrict__ VT, u16* __restrict__ AO,
                                                 u16* __restrict__ AOP, float* __restrict__ lpart,
                                                 int nsplit) {
  __shared__ u16 Kl[2][64][64];
  __shared__ u16 Vl[2][64][64];
  const int tid = threadIdx.x;
  const int wv = tid >> 6, lane = tid & 63;
  const int lr = lane & 15, quad = lane >> 4;
  const int bh = blockIdx.y;
  const int b_ = bh >> 2, head = bh & 3;
  const int qbase = blockIdx.x * 256 + wv * 64;
  const int sp = blockIdx.z;
  const int nchunk = 64 / nsplit, kcg0 = sp * nchunk;
  const u16* Qh = Q + (size_t)bh * Ss * HD;
  const u16* Kh = K + (size_t)bh * Ss * HD;
  const u16* Vh = VT + (size_t)bh * HD * Ss;  // [d][perm(s)]

  bf16x8 qb[4][2];
#pragma unroll
  for (int nt = 0; nt < 4; nt++)
#pragma unroll
    for (int ks = 0; ks < 2; ks++)
      qb[nt][ks] = ldfrag(Qh + (size_t)(qbase + nt * 16 + lr) * HD + ks * 32 + quad * 8);

  u16x8 ov;
#pragma unroll
  for (int j = 0; j < 8; j++) ov[j] = 0x3F80;
  const bf16x8 ones = __builtin_bit_cast(bf16x8, ov);

  f32x4 O[4][4] = {};
  f32x4 lacc[4] = {};

  u16x8 pf[4];
  const int srow = tid >> 3, sseg = tid & 7;
  const int sg = (sseg ^ (srow & 7)) * 8;  // swizzled granule (same for e=0/1: rows differ by 32)
  auto load_chunk = [&](int kc) {
#pragma unroll
    for (int e = 0; e < 2; e++) {
      pf[e] = *(const u16x8*)(Kh + ((size_t)((kcg0 + kc) * 64 + srow + e * 32) << 6) + sseg * 8);
      pf[2 + e] = *(const u16x8*)(Vh + ((size_t)(srow + e * 32) << 12) + (kcg0 + kc) * 64 + sseg * 8);
    }
  };
  auto store_chunk = [&](int buf) {
#pragma unroll
    for (int e = 0; e < 2; e++) {
      *(u16x8*)&Kl[buf][srow + e * 32][sg] = pf[e];
      *(u16x8*)&Vl[buf][srow + e * 32][sg] = pf[2 + e];
    }
  };

  load_chunk(0);
  store_chunk(0);
  if (nchunk > 1) load_chunk(1);
  __syncthreads();

  for (int kc = 0; kc < nchunk; kc++) {
    const int cur = kc & 1;
    if (kc + 1 < nchunk) {
      store_chunk(cur ^ 1);
      if (kc + 2 < nchunk) load_chunk(kc + 2);
    }

    f32x4 St[4][4] = {};
#pragma unroll
    for (int ks = 0; ks < 2; ks++) {
      bf16x8 ka[4];
#pragma unroll
      for (int kt = 0; kt < 4; kt++) {
        int g = ((ks * 4 + quad) ^ (lr & 7)) * 8;
        ka[kt] = ldfrag(&Kl[cur][kt * 16 + lr][g]);
      }
      __builtin_amdgcn_s_setprio(1);
#pragma unroll
      for (int kt = 0; kt < 4; kt++)
#pragma unroll
        for (int nt = 0; nt < 4; nt++)
          St[kt][nt] = __builtin_amdgcn_mfma_f32_16x16x32_bf16(ka[kt], qb[nt][ks], St[kt][nt], 0, 0, 0);
      __builtin_amdgcn_s_setprio(0);
    }

    uint32_t pk[4][4][2];
#pragma unroll
    for (int kt = 0; kt < 4; kt++)
#pragma unroll
      for (int nt = 0; nt < 4; nt++) {
        float p0 = __builtin_amdgcn_exp2f(St[kt][nt][0]);
        float p1 = __builtin_amdgcn_exp2f(St[kt][nt][1]);
        float p2 = __builtin_amdgcn_exp2f(St[kt][nt][2]);
        float p3 = __builtin_amdgcn_exp2f(St[kt][nt][3]);
        pk[kt][nt][0] = pack2bf_trunc(p0, p1);
        pk[kt][nt][1] = pack2bf_trunc(p2, p3);
      }

#pragma unroll
    for (int ks = 0; ks < 2; ks++) {
      bf16x8 pa[4];
#pragma unroll
      for (int mt = 0; mt < 4; mt++) {
        u32x4 t = {pk[2 * ks][mt][0], pk[2 * ks][mt][1], pk[2 * ks + 1][mt][0], pk[2 * ks + 1][mt][1]};
        pa[mt] = __builtin_bit_cast(bf16x8, t);
      }
#pragma unroll
      for (int dt = 0; dt < 4; dt++) {
        int g = ((ks * 4 + quad) ^ (lr & 7)) * 8;
        bf16x8 vb = ldfrag(&Vl[cur][dt * 16 + lr][g]);
        __builtin_amdgcn_s_setprio(1);
#pragma unroll
        for (int mt = 0; mt < 4; mt++)
          O[mt][dt] = __builtin_amdgcn_mfma_f32_16x16x32_bf16(pa[mt], vb, O[mt][dt], 0, 0, 0);
        __builtin_amdgcn_s_setprio(0);
      }
#pragma unroll
      for (int mt = 0; mt < 4; mt++)
        lacc[mt] = __builtin_amdgcn_mfma_f32_16x16x32_bf16(pa[mt], ones, lacc[mt], 0, 0, 0);
    }

    __syncthreads();
  }

  // epilogue: normalize by this split's l, write bf16 (AO if nsplit==1, else partial slot sp)
  u16* dst = (nsplit == 1) ? AO : (AOP + (size_t)sp * ELEMS);
  if (nsplit > 1 && lr == 0) {
    float* lp = lpart + (size_t)sp * (16 * Ss) + bh * Ss;
#pragma unroll
    for (int mt = 0; mt < 4; mt++)
#pragma unroll
      for (int rg = 0; rg < 4; rg++) lp[qbase + mt * 16 + quad * 4 + rg] = lacc[mt][rg];
  }
#pragma unroll
  for (int mt = 0; mt < 4; mt++)
#pragma unroll
    for (int rg = 0; rg < 4; rg++) {
      float inv = 1.0f / lacc[mt][rg];
      int s = qbase + mt * 16 + quad * 4 + rg;
#pragma unroll
      for (int dt = 0; dt < 4; dt++)
        dst[((size_t)(b_ * Ss + s) << 8) + head * 64 + dt * 16 + lr] = f2bf(O[mt][dt][rg] * inv);
    }
}

// ---------------- kernel 3 (fused combine + oproj): y^T = w_o * combine(aop)^T + b_o ----------------
// 256 threads, 128(c) x 128(n) tile, grid (128, 2) = 256 blocks (full GPU).
// B-staging does l-weighted average of normalized bf16 partials over nsplit splits.
__global__ __launch_bounds__(256) void k_oproj(const u16* __restrict__ wo, const u16* __restrict__ ao,
                                               const u16* __restrict__ AOP, const float* __restrict__ lpart,
                                               const float* __restrict__ bo, float* __restrict__ y, int nsplit) {
  __shared__ u16 As[128][40], Bs[128][40];
  const int tid = threadIdx.x;
  const int wv = tid >> 6, lane = tid & 63;
  const int wm = wv >> 1, wn = wv & 1;
  const int lr = lane & 15, quad = lane >> 4;
  const int n0 = blockIdx.x * 128;
  const int m0 = blockIdx.y * 128;
  f32x4 acc[4][4] = {};
  for (int k0 = 0; k0 < 256; k0 += 32) {
    __syncthreads();
    stage_tile(wo, 256, m0, k0, As, tid);
#pragma unroll
    for (int e = 0; e < 2; e++) {  // B: 128 n-rows x 32 c-cols, l-weighted combine
      int c = tid + e * 256;
      int row = c >> 2, seg = c & 3;
      int bs = n0 + row, cc = k0 + seg * 8;
      u16x8 t;
      if (nsplit == 1) {
        t = *(const u16x8*)(ao + ((size_t)bs << 8) + cc);
      } else {
        int b = bs >> 12, s = bs & 4095, head = cc >> 6;
        int li = (b * 4 + head) * Ss + s;
        float accv[8] = {0.f, 0.f, 0.f, 0.f, 0.f, 0.f, 0.f, 0.f};
        float lsum = 0.f;
        for (int spl = 0; spl < nsplit; spl++) {
          float l = lpart[(size_t)spl * (16 * Ss) + li];
          u16x8 a = *(const u16x8*)(AOP + (size_t)spl * ELEMS + ((size_t)bs << 8) + cc);
          lsum += l;
#pragma unroll
          for (int i = 0; i < 8; i++) accv[i] += l * bf2f(a[i]);
        }
        float inv = 1.0f / lsum;
#pragma unroll
        for (int i = 0; i < 8; i++) t[i] = f2bf(accv[i] * inv);
      }
      *(u16x8*)&Bs[row][seg * 8] = t;
    }
    __syncthreads();
    bf16x8 a[4], b[4];
#pragma unroll
    for (int mt = 0; mt < 4; mt++) a[mt] = ldfrag(&As[wm * 64 + mt * 16 + lr][quad * 8]);
#pragma unroll
    for (int nt = 0; nt < 4; nt++) b[nt] = ldfrag(&Bs[wn * 64 + nt * 16 + lr][quad * 8]);
#pragma unroll
    for (int mt = 0; mt < 4; mt++)
#pragma unroll
      for (int nt = 0; nt < 4; nt++)
        acc[mt][nt] = __builtin_amdgcn_mfma_f32_16x16x32_bf16(a[mt], b[nt], acc[mt][nt], 0, 0, 0);
  }
#pragma unroll
  for (int mt = 0; mt < 4; mt++)
#pragma unroll
    for (int rg = 0; rg < 4; rg++) {
      int c = m0 + wm * 64 + mt * 16 + quad * 4 + rg;
      float bc = bo[c];
#pragma unroll
      for (int nt = 0; nt < 4; nt++) {
        int col = n0 + wn * 64 + nt * 16 + lr;
        int b_ = col >> 12, s = col & 4095;
        y[((size_t)(b_ * Cc + c) << 12) + s] = acc[mt][nt][rg] + bc;
      }
    }
}

extern "C" void kernel_launch(void* const* d_in, const int* in_sizes, int n_in,
                              void* d_out, int out_size, void* d_ws, size_t ws_size,
                              hipStream_t stream) {
  const float* x = (const float*)d_in[0];
  const float* w_qkv = (const float*)d_in[1];
  const float* b_qkv = (const float*)d_in[2];
  const float* w_o = (const float*)d_in[3];
  const float* b_o = (const float*)d_in[4];
  float* y = (float*)d_out;
  u16* ws = (u16*)d_ws;
  u16* xt = ws;                        // [0, E) — reused as ao (nsplit==1 fallback)
  u16* q = ws + (size_t)ELEMS;
  u16* k = ws + (size_t)2 * ELEMS;
  u16* vt = ws + (size_t)3 * ELEMS;
  u16* ao = xt;
  u16* wqb = ws + (size_t)4 * ELEMS;   // 196608
  u16* wob = wqb + 196608;             // 65536
  const size_t Wu16 = (size_t)4 * ELEMS + 262144;
  // need(n) bytes = bf16 ws incl. n partial slabs, + n*16*Ss f32 for lpart
  auto need = [&](int n) { return (Wu16 + (size_t)n * ELEMS) * 2 + (size_t)n * 16 * Ss * 4; };
  const int nsplit = (ws_size >= need(4)) ? 4 : (ws_size >= need(2)) ? 2 : 1;
  u16* aop = ws + Wu16;                // nsplit*ELEMS u16 normalized partials
  u16* v = aop;                        // plain V aliases aop (dead before k_attn writes)
  float* lpart = (float*)(aop + (size_t)nsplit * ELEMS);

  k_transpose<<<dim3(64, 4, 4), 256, 0, stream>>>(x, xt, w_qkv, w_o, wqb, wob);
  k_qkv<<<dim3(128, 6), 256, 0, stream>>>(xt, wqb, b_qkv, q, k, v);
  k_vt<<<dim3(64, 16), 256, 0, stream>>>(v, vt);
  k_attn<<<dim3(16, 16, nsplit), 256, 0, stream>>>(q, k, vt, ao, aop, lpart, nsplit);
  k_oproj<<<dim3(128, 2), 256, 0, stream>>>(wob, ao, aop, lpart, b_o, y, nsplit);
}

// Round 2
// 189.044 us; speedup vs baseline: 3.4455x; 3.4455x over previous
//
#include <hip/hip_runtime.h>
#include <stdint.h>

#define DI __device__ __forceinline__

typedef __attribute__((ext_vector_type(8))) __bf16 bf16x8;
typedef __attribute__((ext_vector_type(8))) unsigned short u16x8;
typedef __attribute__((ext_vector_type(4))) float f32x4;
typedef __attribute__((ext_vector_type(4))) uint32_t u32x4;
typedef unsigned short u16;

constexpr int Bb = 4, Cc = 256, Ss = 4096, HD = 64;
constexpr int ELEMS = Bb * Cc * Ss;  // 4194304

DI float bf2f(u16 h) { union { unsigned u; float f; } x; x.u = ((unsigned)h) << 16; return x.f; }
DI u16 f2bf(float f) {
  union { float f; unsigned u; } x; x.f = f;
  return (u16)((x.u + 0x7FFFu + ((x.u >> 16) & 1u)) >> 16);
}
DI uint32_t pack2bf_trunc(float a, float b) {  // low16=bf(a), high16=bf(b), truncating
  union { float f; uint32_t u; } xa, xb;
  xa.f = a; xb.f = b;
  return __builtin_amdgcn_perm(xb.u, xa.u, 0x07060302u);
}
DI bf16x8 ldfrag(const u16* p) { return __builtin_bit_cast(bf16x8, *(const u16x8*)p); }

// ---------------- kernel 0: x (B,C,S) fp32 -> xt (B,S,C) bf16; + weight conversion fused ----------------
// LDS uses XOR column-block swizzle: element (r,c) lives at T[r][((c>>3)^((r>>3)&7))*8 + (c&7)].
// Write: vector u16x8, ~2-way banks. Read: scalar, all-32-banks distinct (was 16-way conflicted).
__global__ __launch_bounds__(256) void k_transpose(const float* __restrict__ x, u16* __restrict__ xt,
                                                   const float* __restrict__ wq, const float* __restrict__ wo,
                                                   u16* __restrict__ wqb, u16* __restrict__ wob) {
  __shared__ u16 T[64][72];
  const int st = blockIdx.x, ct = blockIdx.y, b = blockIdx.z;
  const int tid = threadIdx.x;
  // fused weight conversion: 1024 blocks x 256 threads == 262144 == 196608 + 65536
  {
    int flat = blockIdx.x + 64 * blockIdx.y + 256 * blockIdx.z;
    int widx = flat * 256 + tid;
    if (widx < 196608) wqb[widx] = f2bf(wq[widx]);
    else wob[widx - 196608] = f2bf(wo[widx - 196608]);
  }
#pragma unroll
  for (int e = 0; e < 2; e++) {
    int ss = tid + e * 256;
    int r = ss >> 3, seg = ss & 7;
    size_t base = ((size_t)(b * Cc + ct * 64 + r) << 12) + st * 64 + seg * 8;
    u16x8 t;
#pragma unroll
    for (int j = 0; j < 8; j++) t[j] = f2bf(x[base + j]);
    *(u16x8*)&T[r][(seg ^ ((r >> 3) & 7)) * 8] = t;
  }
  __syncthreads();
#pragma unroll
  for (int e = 0; e < 2; e++) {
    int ss = tid + e * 256;
    int sr = ss >> 3, cseg = ss & 7;
    u16x8 o;
#pragma unroll
    for (int j = 0; j < 8; j++) {
      int row = cseg * 8 + j;
      o[j] = T[row][(((sr >> 3) ^ cseg) * 8) + (sr & 7)];
    }
    *(u16x8*)(xt + ((size_t)(b * Ss + st * 64 + sr) << 8) + ct * 64 + cseg * 8) = o;
  }
}

// ---- shared GEMM staging: rows [r0,r0+128) x cols [k0,k0+32), pitch-40 LDS ----
DI void stage_tile(const u16* __restrict__ src, int pitch, int r0, int k0, u16 (*dst)[40], int tid) {
#pragma unroll
  for (int e = 0; e < 2; e++) {
    int c = tid + e * 256;
    int row = c >> 2, seg = c & 3;
    u16x8 t = *(const u16x8*)(src + (size_t)(r0 + row) * pitch + k0 + seg * 8);
    *(u16x8*)&dst[row][seg * 8] = t;
  }
}

// ---------------- kernel 1: qkv GEMM.  q:[bh][s][64]*(0.125*log2e)  k,v:[bh][s][64] ----------------
__global__ __launch_bounds__(256) void k_qkv(const u16* __restrict__ xt, const u16* __restrict__ w,
                                             const float* __restrict__ bias,
                                             u16* __restrict__ q, u16* __restrict__ kk_, u16* __restrict__ vv_) {
  __shared__ u16 As[128][40], Bs[128][40];
  const int tid = threadIdx.x;
  const int wv = tid >> 6, lane = tid & 63;
  const int wm = wv >> 1, wn = wv & 1;
  const int lr = lane & 15, quad = lane >> 4;
  const int r0 = blockIdx.x * 128;
  const int j0 = blockIdx.y * 128;
  f32x4 acc[4][4] = {};
  for (int k0 = 0; k0 < 256; k0 += 32) {
    __syncthreads();
    stage_tile(xt, 256, r0, k0, As, tid);
    stage_tile(w, 256, j0, k0, Bs, tid);
    __syncthreads();
    bf16x8 a[4], b[4];
#pragma unroll
    for (int mt = 0; mt < 4; mt++) a[mt] = ldfrag(&As[wm * 64 + mt * 16 + lr][quad * 8]);
#pragma unroll
    for (int nt = 0; nt < 4; nt++) b[nt] = ldfrag(&Bs[wn * 64 + nt * 16 + lr][quad * 8]);
#pragma unroll
    for (int mt = 0; mt < 4; mt++)
#pragma unroll
      for (int nt = 0; nt < 4; nt++)
        acc[mt][nt] = __builtin_amdgcn_mfma_f32_16x16x32_bf16(a[mt], b[nt], acc[mt][nt], 0, 0, 0);
  }
#pragma unroll
  for (int nt = 0; nt < 4; nt++) {
    int j = j0 + wn * 64 + nt * 16 + lr;
    float bj = bias[j];
    int part = j >> 8, cc = j & 255, head = cc >> 6, d = cc & 63;
    u16* outp = (part == 0) ? q : (part == 1) ? kk_ : vv_;
    float sc = (part == 0) ? 0.18033688f : 1.0f;  // 0.125*log2(e), exp2-domain scores
#pragma unroll
    for (int mt = 0; mt < 4; mt++)
#pragma unroll
      for (int rg = 0; rg < 4; rg++) {
        int row = r0 + wm * 64 + mt * 16 + quad * 4 + rg;
        int b_ = row >> 12, s = row & 4095;
        outp[((size_t)((b_ * 4 + head) * Ss + s) << 6) + d] = f2bf((acc[mt][nt][rg] + bj) * sc);
      }
  }
}

// ---------------- v [bh][s][64] -> vt [bh][d][chunk*64 + slot] (key-permuted transpose) ----------------
// Same XOR swizzle on the LDS tile to break read conflicts.
__global__ __launch_bounds__(256) void k_vt(const u16* __restrict__ v, u16* __restrict__ vt) {
  __shared__ u16 T[64][72];
  const int chunk = blockIdx.x, bh = blockIdx.y;
  const int tid = threadIdx.x;
#pragma unroll
  for (int e = 0; e < 2; e++) {
    int row = (tid >> 3) + e * 32, seg = tid & 7;
    *(u16x8*)&T[row][(seg ^ ((row >> 3) & 7)) * 8] =
        *(const u16x8*)(v + ((size_t)(bh * Ss + chunk * 64 + row) << 6) + seg * 8);
  }
  __syncthreads();
#pragma unroll
  for (int e = 0; e < 2; e++) {
    int d = (tid >> 3) + e * 32, seg = tid & 7;
    u16x8 o;
#pragma unroll
    for (int j = 0; j < 8; j++) {
      int slot = seg * 8 + j;
      int t = (((slot >> 5) & 1) << 1) | ((slot >> 2) & 1);
      int w6 = t * 16 + (((slot >> 3) & 3) << 2) + (slot & 3);
      o[j] = T[w6][(((d >> 3) ^ ((w6 >> 3) & 7)) * 8) + (d & 7)];
    }
    *(u16x8*)(vt + ((size_t)(bh * 64 + d) << 12) + chunk * 64 + seg * 8) = o;
  }
}

// ---------------- kernel 2: flash attention, S^T form, exp2 no-max softmax ----------------
// 64 q/wave, 256 q-rows/block, double-buffered staging with early stores, l via ones-MFMA.
// K-split: each split writes NORMALIZED bf16 partials + l; combine is an l-weighted average.
// LDS tiles [64][64] with 16B-granule XOR swizzle (g ^= row&7): conflict-free reads AND writes.
// __launch_bounds__(256,2): do NOT raise the waves/EU hint — (256,4) capped regs at 128 and
// spilled the 128-reg accumulator state to scratch (1 GB FETCH, MfmaUtil 0.4%). VGPR=112 already
// gives 4 waves/SIMD naturally; nsplit=4 supplies the 4 blocks/CU.
__global__ __launch_bounds__(256, 2) void k_attn(const u16* __restrict__ Q, const u16* __restrict__ K,
                                                 const u16* __restrict__ VT, u16* __restrict__ AO,
                                                 u16* __restrict__ AOP, float* __restrict__ lpart,
                                                 int nsplit) {
  __shared__ u16 Kl[2][64][64];
  __shared__ u16 Vl[2][64][64];
  const int tid = threadIdx.x;
  const int wv = tid >> 6, lane = tid & 63;
  const int lr = lane & 15, quad = lane >> 4;
  const int bh = blockIdx.y;
  const int b_ = bh >> 2, head = bh & 3;
  const int qbase = blockIdx.x * 256 + wv * 64;
  const int sp = blockIdx.z;
  const int nchunk = 64 / nsplit, kcg0 = sp * nchunk;
  const u16* Qh = Q + (size_t)bh * Ss * HD;
  const u16* Kh = K + (size_t)bh * Ss * HD;
  const u16* Vh = VT + (size_t)bh * HD * Ss;  // [d][perm(s)]

  bf16x8 qb[4][2];
#pragma unroll
  for (int nt = 0; nt < 4; nt++)
#pragma unroll
    for (int ks = 0; ks < 2; ks++)
      qb[nt][ks] = ldfrag(Qh + (size_t)(qbase + nt * 16 + lr) * HD + ks * 32 + quad * 8);

  u16x8 ov;
#pragma unroll
  for (int j = 0; j < 8; j++) ov[j] = 0x3F80;
  const bf16x8 ones = __builtin_bit_cast(bf16x8, ov);

  f32x4 O[4][4] = {};
  f32x4 lacc[4] = {};

  u16x8 pf[4];
  const int srow = tid >> 3, sseg = tid & 7;
  const int sg = (sseg ^ (srow & 7)) * 8;  // swizzled granule (same for e=0/1: rows differ by 32)
  auto load_chunk = [&](int kc) {
#pragma unroll
    for (int e = 0; e < 2; e++) {
      pf[e] = *(const u16x8*)(Kh + ((size_t)((kcg0 + kc) * 64 + srow + e * 32) << 6) + sseg * 8);
      pf[2 + e] = *(const u16x8*)(Vh + ((size_t)(srow + e * 32) << 12) + (kcg0 + kc) * 64 + sseg * 8);
    }
  };
  auto store_chunk = [&](int buf) {
#pragma unroll
    for (int e = 0; e < 2; e++) {
      *(u16x8*)&Kl[buf][srow + e * 32][sg] = pf[e];
      *(u16x8*)&Vl[buf][srow + e * 32][sg] = pf[2 + e];
    }
  };

  load_chunk(0);
  store_chunk(0);
  if (nchunk > 1) load_chunk(1);
  __syncthreads();

  for (int kc = 0; kc < nchunk; kc++) {
    const int cur = kc & 1;
    if (kc + 1 < nchunk) {
      store_chunk(cur ^ 1);
      if (kc + 2 < nchunk) load_chunk(kc + 2);
    }

    f32x4 St[4][4] = {};
#pragma unroll
    for (int ks = 0; ks < 2; ks++) {
      bf16x8 ka[4];
#pragma unroll
      for (int kt = 0; kt < 4; kt++) {
        int g = ((ks * 4 + quad) ^ (lr & 7)) * 8;
        ka[kt] = ldfrag(&Kl[cur][kt * 16 + lr][g]);
      }
      __builtin_amdgcn_s_setprio(1);
#pragma unroll
      for (int kt = 0; kt < 4; kt++)
#pragma unroll
        for (int nt = 0; nt < 4; nt++)
          St[kt][nt] = __builtin_amdgcn_mfma_f32_16x16x32_bf16(ka[kt], qb[nt][ks], St[kt][nt], 0, 0, 0);
      __builtin_amdgcn_s_setprio(0);
    }

    uint32_t pk[4][4][2];
#pragma unroll
    for (int kt = 0; kt < 4; kt++)
#pragma unroll
      for (int nt = 0; nt < 4; nt++) {
        float p0 = __builtin_amdgcn_exp2f(St[kt][nt][0]);
        float p1 = __builtin_amdgcn_exp2f(St[kt][nt][1]);
        float p2 = __builtin_amdgcn_exp2f(St[kt][nt][2]);
        float p3 = __builtin_amdgcn_exp2f(St[kt][nt][3]);
        pk[kt][nt][0] = pack2bf_trunc(p0, p1);
        pk[kt][nt][1] = pack2bf_trunc(p2, p3);
      }

#pragma unroll
    for (int ks = 0; ks < 2; ks++) {
      bf16x8 pa[4];
#pragma unroll
      for (int mt = 0; mt < 4; mt++) {
        u32x4 t = {pk[2 * ks][mt][0], pk[2 * ks][mt][1], pk[2 * ks + 1][mt][0], pk[2 * ks + 1][mt][1]};
        pa[mt] = __builtin_bit_cast(bf16x8, t);
      }
#pragma unroll
      for (int dt = 0; dt < 4; dt++) {
        int g = ((ks * 4 + quad) ^ (lr & 7)) * 8;
        bf16x8 vb = ldfrag(&Vl[cur][dt * 16 + lr][g]);
        __builtin_amdgcn_s_setprio(1);
#pragma unroll
        for (int mt = 0; mt < 4; mt++)
          O[mt][dt] = __builtin_amdgcn_mfma_f32_16x16x32_bf16(pa[mt], vb, O[mt][dt], 0, 0, 0);
        __builtin_amdgcn_s_setprio(0);
      }
#pragma unroll
      for (int mt = 0; mt < 4; mt++)
        lacc[mt] = __builtin_amdgcn_mfma_f32_16x16x32_bf16(pa[mt], ones, lacc[mt], 0, 0, 0);
    }

    __syncthreads();
  }

  // epilogue: normalize by this split's l, write bf16 (AO if nsplit==1, else partial slot sp)
  u16* dst = (nsplit == 1) ? AO : (AOP + (size_t)sp * ELEMS);
  if (nsplit > 1 && lr == 0) {
    float* lp = lpart + (size_t)sp * (16 * Ss) + bh * Ss;
#pragma unroll
    for (int mt = 0; mt < 4; mt++)
#pragma unroll
      for (int rg = 0; rg < 4; rg++) lp[qbase + mt * 16 + quad * 4 + rg] = lacc[mt][rg];
  }
#pragma unroll
  for (int mt = 0; mt < 4; mt++)
#pragma unroll
    for (int rg = 0; rg < 4; rg++) {
      float inv = 1.0f / lacc[mt][rg];
      int s = qbase + mt * 16 + quad * 4 + rg;
#pragma unroll
      for (int dt = 0; dt < 4; dt++)
        dst[((size_t)(b_ * Ss + s) << 8) + head * 64 + dt * 16 + lr] = f2bf(O[mt][dt][rg] * inv);
    }
}

// ---------------- kernel 3 (fused combine + oproj): y^T = w_o * combine(aop)^T + b_o ----------------
// 256 threads, 128(c) x 128(n) tile, grid (128, 2) = 256 blocks (full GPU).
// B-staging does l-weighted average of normalized bf16 partials over nsplit splits.
__global__ __launch_bounds__(256) void k_oproj(const u16* __restrict__ wo, const u16* __restrict__ ao,
                                               const u16* __restrict__ AOP, const float* __restrict__ lpart,
                                               const float* __restrict__ bo, float* __restrict__ y, int nsplit) {
  __shared__ u16 As[128][40], Bs[128][40];
  const int tid = threadIdx.x;
  const int wv = tid >> 6, lane = tid & 63;
  const int wm = wv >> 1, wn = wv & 1;
  const int lr = lane & 15, quad = lane >> 4;
  const int n0 = blockIdx.x * 128;
  const int m0 = blockIdx.y * 128;
  f32x4 acc[4][4] = {};
  for (int k0 = 0; k0 < 256; k0 += 32) {
    __syncthreads();
    stage_tile(wo, 256, m0, k0, As, tid);
#pragma unroll
    for (int e = 0; e < 2; e++) {  // B: 128 n-rows x 32 c-cols, l-weighted combine
      int c = tid + e * 256;
      int row = c >> 2, seg = c & 3;
      int bs = n0 + row, cc = k0 + seg * 8;
      u16x8 t;
      if (nsplit == 1) {
        t = *(const u16x8*)(ao + ((size_t)bs << 8) + cc);
      } else {
        int b = bs >> 12, s = bs & 4095, head = cc >> 6;
        int li = (b * 4 + head) * Ss + s;
        float accv[8] = {0.f, 0.f, 0.f, 0.f, 0.f, 0.f, 0.f, 0.f};
        float lsum = 0.f;
        for (int spl = 0; spl < nsplit; spl++) {
          float l = lpart[(size_t)spl * (16 * Ss) + li];
          u16x8 a = *(const u16x8*)(AOP + (size_t)spl * ELEMS + ((size_t)bs << 8) + cc);
          lsum += l;
#pragma unroll
          for (int i = 0; i < 8; i++) accv[i] += l * bf2f(a[i]);
        }
        float inv = 1.0f / lsum;
#pragma unroll
        for (int i = 0; i < 8; i++) t[i] = f2bf(accv[i] * inv);
      }
      *(u16x8*)&Bs[row][seg * 8] = t;
    }
    __syncthreads();
    bf16x8 a[4], b[4];
#pragma unroll
    for (int mt = 0; mt < 4; mt++) a[mt] = ldfrag(&As[wm * 64 + mt * 16 + lr][quad * 8]);
#pragma unroll
    for (int nt = 0; nt < 4; nt++) b[nt] = ldfrag(&Bs[wn * 64 + nt * 16 + lr][quad * 8]);
#pragma unroll
    for (int mt = 0; mt < 4; mt++)
#pragma unroll
      for (int nt = 0; nt < 4; nt++)
        acc[mt][nt] = __builtin_amdgcn_mfma_f32_16x16x32_bf16(a[mt], b[nt], acc[mt][nt], 0, 0, 0);
  }
#pragma unroll
  for (int mt = 0; mt < 4; mt++)
#pragma unroll
    for (int rg = 0; rg < 4; rg++) {
      int c = m0 + wm * 64 + mt * 16 + quad * 4 + rg;
      float bc = bo[c];
#pragma unroll
      for (int nt = 0; nt < 4; nt++) {
        int col = n0 + wn * 64 + nt * 16 + lr;
        int b_ = col >> 12, s = col & 4095;
        y[((size_t)(b_ * Cc + c) << 12) + s] = acc[mt][nt][rg] + bc;
      }
    }
}

extern "C" void kernel_launch(void* const* d_in, const int* in_sizes, int n_in,
                              void* d_out, int out_size, void* d_ws, size_t ws_size,
                              hipStream_t stream) {
  const float* x = (const float*)d_in[0];
  const float* w_qkv = (const float*)d_in[1];
  const float* b_qkv = (const float*)d_in[2];
  const float* w_o = (const float*)d_in[3];
  const float* b_o = (const float*)d_in[4];
  float* y = (float*)d_out;
  u16* ws = (u16*)d_ws;
  u16* xt = ws;                        // [0, E) — reused as ao (nsplit==1 fallback)
  u16* q = ws + (size_t)ELEMS;
  u16* k = ws + (size_t)2 * ELEMS;
  u16* vt = ws + (size_t)3 * ELEMS;
  u16* ao = xt;
  u16* wqb = ws + (size_t)4 * ELEMS;   // 196608
  u16* wob = wqb + 196608;             // 65536
  const size_t Wu16 = (size_t)4 * ELEMS + 262144;
  // need(n) bytes = bf16 ws incl. n partial slabs, + n*16*Ss f32 for lpart
  auto need = [&](int n) { return (Wu16 + (size_t)n * ELEMS) * 2 + (size_t)n * 16 * Ss * 4; };
  const int nsplit = (ws_size >= need(4)) ? 4 : (ws_size >= need(2)) ? 2 : 1;
  u16* aop = ws + Wu16;                // nsplit*ELEMS u16 normalized partials
  u16* v = aop;                        // plain V aliases aop (dead before k_attn writes)
  float* lpart = (float*)(aop + (size_t)nsplit * ELEMS);

  k_transpose<<<dim3(64, 4, 4), 256, 0, stream>>>(x, xt, w_qkv, w_o, wqb, wob);
  k_qkv<<<dim3(128, 6), 256, 0, stream>>>(xt, wqb, b_qkv, q, k, v);
  k_vt<<<dim3(64, 16), 256, 0, stream>>>(v, vt);
  k_attn<<<dim3(16, 16, nsplit), 256, 0, stream>>>(q, k, vt, ao, aop, lpart, nsplit);
  k_oproj<<<dim3(128, 2), 256, 0, stream>>>(wob, ao, aop, lpart, b_o, y, nsplit);
}

// Round 3
// 188.820 us; speedup vs baseline: 3.4496x; 1.0012x over previous
//
#include <hip/hip_runtime.h>
#include <stdint.h>

#define DI __device__ __forceinline__

typedef __attribute__((ext_vector_type(8))) __bf16 bf16x8;
typedef __attribute__((ext_vector_type(8))) unsigned short u16x8;
typedef __attribute__((ext_vector_type(4))) float f32x4;
typedef __attribute__((ext_vector_type(4))) uint32_t u32x4;
typedef unsigned short u16;

constexpr int Bb = 4, Cc = 256, Ss = 4096, HD = 64;
constexpr int ELEMS = Bb * Cc * Ss;  // 4194304

DI float bf2f(u16 h) { union { unsigned u; float f; } x; x.u = ((unsigned)h) << 16; return x.f; }
DI u16 f2bf(float f) {
  union { float f; unsigned u; } x; x.f = f;
  return (u16)((x.u + 0x7FFFu + ((x.u >> 16) & 1u)) >> 16);
}
DI uint32_t pack2bf_trunc(float a, float b) {  // low16=bf(a), high16=bf(b), truncating
  union { float f; uint32_t u; } xa, xb;
  xa.f = a; xb.f = b;
  return __builtin_amdgcn_perm(xb.u, xa.u, 0x07060302u);
}
DI bf16x8 ldfrag(const u16* p) { return __builtin_bit_cast(bf16x8, *(const u16x8*)p); }

// async global->LDS DMA, 16B per lane. LDS dest = wave-uniform base + lane*16 (linear);
// source address is per-lane (carries the swizzle).
DI void g2l16(const u16* g, u16* l) {
  __builtin_amdgcn_global_load_lds((const __attribute__((address_space(1))) uint32_t*)(const void*)g,
                                   (__attribute__((address_space(3))) uint32_t*)(void*)l, 16, 0, 0);
}

// ---------------- kernel 0: x (B,C,S) fp32 -> xt (B,S,C) bf16; + weight conversion fused ----------------
// LDS uses XOR column-block swizzle: element (r,c) lives at T[r][((c>>3)^((r>>3)&7))*8 + (c&7)].
// Write: vector u16x8, ~2-way banks. Read: scalar, all-32-banks distinct (was 16-way conflicted).
__global__ __launch_bounds__(256) void k_transpose(const float* __restrict__ x, u16* __restrict__ xt,
                                                   const float* __restrict__ wq, const float* __restrict__ wo,
                                                   u16* __restrict__ wqb, u16* __restrict__ wob) {
  __shared__ u16 T[64][72];
  const int st = blockIdx.x, ct = blockIdx.y, b = blockIdx.z;
  const int tid = threadIdx.x;
  // fused weight conversion: 1024 blocks x 256 threads == 262144 == 196608 + 65536
  {
    int flat = blockIdx.x + 64 * blockIdx.y + 256 * blockIdx.z;
    int widx = flat * 256 + tid;
    if (widx < 196608) wqb[widx] = f2bf(wq[widx]);
    else wob[widx - 196608] = f2bf(wo[widx - 196608]);
  }
#pragma unroll
  for (int e = 0; e < 2; e++) {
    int ss = tid + e * 256;
    int r = ss >> 3, seg = ss & 7;
    size_t base = ((size_t)(b * Cc + ct * 64 + r) << 12) + st * 64 + seg * 8;
    u16x8 t;
#pragma unroll
    for (int j = 0; j < 8; j++) t[j] = f2bf(x[base + j]);
    *(u16x8*)&T[r][(seg ^ ((r >> 3) & 7)) * 8] = t;
  }
  __syncthreads();
#pragma unroll
  for (int e = 0; e < 2; e++) {
    int ss = tid + e * 256;
    int sr = ss >> 3, cseg = ss & 7;
    u16x8 o;
#pragma unroll
    for (int j = 0; j < 8; j++) {
      int row = cseg * 8 + j;
      o[j] = T[row][(((sr >> 3) ^ cseg) * 8) + (sr & 7)];
    }
    *(u16x8*)(xt + ((size_t)(b * Ss + st * 64 + sr) << 8) + ct * 64 + cseg * 8) = o;
  }
}

// ---- shared GEMM staging: rows [r0,r0+128) x cols [k0,k0+32), pitch-40 LDS ----
DI void stage_tile(const u16* __restrict__ src, int pitch, int r0, int k0, u16 (*dst)[40], int tid) {
#pragma unroll
  for (int e = 0; e < 2; e++) {
    int c = tid + e * 256;
    int row = c >> 2, seg = c & 3;
    u16x8 t = *(const u16x8*)(src + (size_t)(r0 + row) * pitch + k0 + seg * 8);
    *(u16x8*)&dst[row][seg * 8] = t;
  }
}

// ---------------- kernel 1: qkv GEMM.  q:[bh][s][64]*(0.125*log2e)  k,v:[bh][s][64] ----------------
__global__ __launch_bounds__(256) void k_qkv(const u16* __restrict__ xt, const u16* __restrict__ w,
                                             const float* __restrict__ bias,
                                             u16* __restrict__ q, u16* __restrict__ kk_, u16* __restrict__ vv_) {
  __shared__ u16 As[128][40], Bs[128][40];
  const int tid = threadIdx.x;
  const int wv = tid >> 6, lane = tid & 63;
  const int wm = wv >> 1, wn = wv & 1;
  const int lr = lane & 15, quad = lane >> 4;
  const int r0 = blockIdx.x * 128;
  const int j0 = blockIdx.y * 128;
  f32x4 acc[4][4] = {};
  for (int k0 = 0; k0 < 256; k0 += 32) {
    __syncthreads();
    stage_tile(xt, 256, r0, k0, As, tid);
    stage_tile(w, 256, j0, k0, Bs, tid);
    __syncthreads();
    bf16x8 a[4], b[4];
#pragma unroll
    for (int mt = 0; mt < 4; mt++) a[mt] = ldfrag(&As[wm * 64 + mt * 16 + lr][quad * 8]);
#pragma unroll
    for (int nt = 0; nt < 4; nt++) b[nt] = ldfrag(&Bs[wn * 64 + nt * 16 + lr][quad * 8]);
#pragma unroll
    for (int mt = 0; mt < 4; mt++)
#pragma unroll
      for (int nt = 0; nt < 4; nt++)
        acc[mt][nt] = __builtin_amdgcn_mfma_f32_16x16x32_bf16(a[mt], b[nt], acc[mt][nt], 0, 0, 0);
  }
#pragma unroll
  for (int nt = 0; nt < 4; nt++) {
    int j = j0 + wn * 64 + nt * 16 + lr;
    float bj = bias[j];
    int part = j >> 8, cc = j & 255, head = cc >> 6, d = cc & 63;
    u16* outp = (part == 0) ? q : (part == 1) ? kk_ : vv_;
    float sc = (part == 0) ? 0.18033688f : 1.0f;  // 0.125*log2(e), exp2-domain scores
#pragma unroll
    for (int mt = 0; mt < 4; mt++)
#pragma unroll
      for (int rg = 0; rg < 4; rg++) {
        int row = r0 + wm * 64 + mt * 16 + quad * 4 + rg;
        int b_ = row >> 12, s = row & 4095;
        outp[((size_t)((b_ * 4 + head) * Ss + s) << 6) + d] = f2bf((acc[mt][nt][rg] + bj) * sc);
      }
  }
}

// ---------------- v [bh][s][64] -> vt [bh][d][chunk*64 + slot] (key-permuted transpose) ----------------
// Same XOR swizzle on the LDS tile to break read conflicts.
__global__ __launch_bounds__(256) void k_vt(const u16* __restrict__ v, u16* __restrict__ vt) {
  __shared__ u16 T[64][72];
  const int chunk = blockIdx.x, bh = blockIdx.y;
  const int tid = threadIdx.x;
#pragma unroll
  for (int e = 0; e < 2; e++) {
    int row = (tid >> 3) + e * 32, seg = tid & 7;
    *(u16x8*)&T[row][(seg ^ ((row >> 3) & 7)) * 8] =
        *(const u16x8*)(v + ((size_t)(bh * Ss + chunk * 64 + row) << 6) + seg * 8);
  }
  __syncthreads();
#pragma unroll
  for (int e = 0; e < 2; e++) {
    int d = (tid >> 3) + e * 32, seg = tid & 7;
    u16x8 o;
#pragma unroll
    for (int j = 0; j < 8; j++) {
      int slot = seg * 8 + j;
      int t = (((slot >> 5) & 1) << 1) | ((slot >> 2) & 1);
      int w6 = t * 16 + (((slot >> 3) & 3) << 2) + (slot & 3);
      o[j] = T[w6][(((d >> 3) ^ ((w6 >> 3) & 7)) * 8) + (d & 7)];
    }
    *(u16x8*)(vt + ((size_t)(bh * 64 + d) << 12) + chunk * 64 + seg * 8) = o;
  }
}

// ---------------- kernel 2: flash attention, S^T form, exp2 no-max softmax ----------------
// Register-minimized restructure for 3 waves/SIMD:
//  - per 16-row kv tile: QK (8 MFMA) -> exp2 -> pack immediately (St transient = 16 regs, was 64)
//  - K/V staged via global_load_lds DMA (pre-swizzled per-lane SOURCE, linear LDS dest,
//    swizzled read — rule "both-sides-or-neither"); no pf regs, no ds_writes, async across chunk
//  - __launch_bounds__(256,3): cap 170 regs vs ~170 natural. (256,4)=cap128 spilled (round 1);
//    (256,2) left true usage at ~256 -> 2 waves/SIMD and grid scaling did nothing (round 2).
// K-split: each split writes NORMALIZED bf16 partials + l; combine is l-weighted average.
__global__ __launch_bounds__(256, 3) void k_attn(const u16* __restrict__ Q, const u16* __restrict__ K,
                                                 const u16* __restrict__ VT, u16* __restrict__ AO,
                                                 u16* __restrict__ AOP, float* __restrict__ lpart,
                                                 int nsplit) {
  __shared__ u16 Kl[2][64][64];
  __shared__ u16 Vl[2][64][64];
  const int tid = threadIdx.x;
  const int wv = tid >> 6, lane = tid & 63;
  const int lr = lane & 15, quad = lane >> 4;
  const int bh = blockIdx.y;
  const int b_ = bh >> 2, head = bh & 3;
  const int qbase = blockIdx.x * 256 + wv * 64;
  const int sp = blockIdx.z;
  const int nchunk = 64 / nsplit, kcg0 = sp * nchunk;
  const u16* Qh = Q + (size_t)bh * Ss * HD;
  const u16* Kh = K + (size_t)bh * Ss * HD;
  const u16* Vh = VT + (size_t)bh * HD * Ss;  // [d][perm(s)]

  bf16x8 qb[4][2];
#pragma unroll
  for (int nt = 0; nt < 4; nt++)
#pragma unroll
    for (int ks = 0; ks < 2; ks++)
      qb[nt][ks] = ldfrag(Qh + (size_t)(qbase + nt * 16 + lr) * HD + ks * 32 + quad * 8);

  u16x8 ov;
#pragma unroll
  for (int j = 0; j < 8; j++) ov[j] = 0x3F80;
  const bf16x8 ones = __builtin_bit_cast(bf16x8, ov);

  f32x4 O[4][4] = {};
  f32x4 lacc[4] = {};

  // DMA staging: wave wv covers rows wv*16 .. wv*16+15 of both 64x64 tiles (2 issues each).
  // Lane l writes LDS granule (row = base + l>>3, slot = l&7); slot p of row r must hold
  // source granule p ^ (r&7)  =>  per-lane source granule = (l&7) ^ (l>>3).
  const int lrow = lane >> 3;                 // 0..7
  const int lseg = ((lane & 7) ^ lrow) * 8;   // source granule offset in elems
  const int kd0 = wv * 16 + lrow;
  const u16* pK0 = Kh + ((size_t)(kcg0 * 64 + kd0) << 6) + lseg;
  const u16* pK1 = pK0 + (8 << 6);
  const u16* pV0 = Vh + ((size_t)kd0 << 12) + kcg0 * 64 + lseg;
  const u16* pV1 = pV0 + ((size_t)8 << 12);
  auto stage = [&](int buf) {
    g2l16(pK0, &Kl[buf][wv * 16][0]);
    g2l16(pK1, &Kl[buf][wv * 16 + 8][0]);
    g2l16(pV0, &Vl[buf][wv * 16][0]);
    g2l16(pV1, &Vl[buf][wv * 16 + 8][0]);
    pK0 += 4096; pK1 += 4096; pV0 += 64; pV1 += 64;  // next chunk
  };

  stage(0);
  __syncthreads();  // implicit vmcnt(0) drains the DMA

  for (int kc = 0; kc < nchunk; kc++) {
    const int cur = kc & 1;
    if (kc + 1 < nchunk) stage(cur ^ 1);  // async into other buffer; drains at loop-end barrier

#pragma unroll
    for (int h = 0; h < 2; h++) {  // kv half: rows h*32 .. h*32+31
      uint32_t pk[2][4][2];
#pragma unroll
      for (int kt2 = 0; kt2 < 2; kt2++) {  // 16-row kv tile within half
        const int krow = (h * 2 + kt2) * 16 + lr;
        bf16x8 ka0 = ldfrag(&Kl[cur][krow][(quad ^ (lr & 7)) * 8]);
        bf16x8 ka1 = ldfrag(&Kl[cur][krow][((4 + quad) ^ (lr & 7)) * 8]);
        f32x4 St[4] = {};
        __builtin_amdgcn_s_setprio(1);
#pragma unroll
        for (int nt = 0; nt < 4; nt++)
          St[nt] = __builtin_amdgcn_mfma_f32_16x16x32_bf16(ka0, qb[nt][0], St[nt], 0, 0, 0);
#pragma unroll
        for (int nt = 0; nt < 4; nt++)
          St[nt] = __builtin_amdgcn_mfma_f32_16x16x32_bf16(ka1, qb[nt][1], St[nt], 0, 0, 0);
        __builtin_amdgcn_s_setprio(0);
#pragma unroll
        for (int nt = 0; nt < 4; nt++) {
          float p0 = __builtin_amdgcn_exp2f(St[nt][0]);
          float p1 = __builtin_amdgcn_exp2f(St[nt][1]);
          float p2 = __builtin_amdgcn_exp2f(St[nt][2]);
          float p3 = __builtin_amdgcn_exp2f(St[nt][3]);
          pk[kt2][nt][0] = pack2bf_trunc(p0, p1);
          pk[kt2][nt][1] = pack2bf_trunc(p2, p3);
        }
      }
      bf16x8 pa[4];
#pragma unroll
      for (int mt = 0; mt < 4; mt++) {
        u32x4 t = {pk[0][mt][0], pk[0][mt][1], pk[1][mt][0], pk[1][mt][1]};
        pa[mt] = __builtin_bit_cast(bf16x8, t);
      }
#pragma unroll
      for (int dt = 0; dt < 4; dt++) {
        bf16x8 vb = ldfrag(&Vl[cur][dt * 16 + lr][((h * 4 + quad) ^ (lr & 7)) * 8]);
        __builtin_amdgcn_s_setprio(1);
#pragma unroll
        for (int mt = 0; mt < 4; mt++)
          O[mt][dt] = __builtin_amdgcn_mfma_f32_16x16x32_bf16(pa[mt], vb, O[mt][dt], 0, 0, 0);
        __builtin_amdgcn_s_setprio(0);
      }
#pragma unroll
      for (int mt = 0; mt < 4; mt++)
        lacc[mt] = __builtin_amdgcn_mfma_f32_16x16x32_bf16(pa[mt], ones, lacc[mt], 0, 0, 0);
    }

    __syncthreads();
  }

  // epilogue: normalize by this split's l, write bf16 (AO if nsplit==1, else partial slot sp)
  u16* dst = (nsplit == 1) ? AO : (AOP + (size_t)sp * ELEMS);
  if (nsplit > 1 && lr == 0) {
    float* lp = lpart + (size_t)sp * (16 * Ss) + bh * Ss;
#pragma unroll
    for (int mt = 0; mt < 4; mt++)
#pragma unroll
      for (int rg = 0; rg < 4; rg++) lp[qbase + mt * 16 + quad * 4 + rg] = lacc[mt][rg];
  }
#pragma unroll
  for (int mt = 0; mt < 4; mt++)
#pragma unroll
    for (int rg = 0; rg < 4; rg++) {
      float inv = 1.0f / lacc[mt][rg];
      int s = qbase + mt * 16 + quad * 4 + rg;
#pragma unroll
      for (int dt = 0; dt < 4; dt++)
        dst[((size_t)(b_ * Ss + s) << 8) + head * 64 + dt * 16 + lr] = f2bf(O[mt][dt][rg] * inv);
    }
}

// ---------------- kernel 3 (fused combine + oproj): y^T = w_o * combine(aop)^T + b_o ----------------
// 256 threads, 128(c) x 128(n) tile, grid (128, 2) = 256 blocks (full GPU).
// B-staging does l-weighted average of normalized bf16 partials over nsplit splits.
__global__ __launch_bounds__(256) void k_oproj(const u16* __restrict__ wo, const u16* __restrict__ ao,
                                               const u16* __restrict__ AOP, const float* __restrict__ lpart,
                                               const float* __restrict__ bo, float* __restrict__ y, int nsplit) {
  __shared__ u16 As[128][40], Bs[128][40];
  const int tid = threadIdx.x;
  const int wv = tid >> 6, lane = tid & 63;
  const int wm = wv >> 1, wn = wv & 1;
  const int lr = lane & 15, quad = lane >> 4;
  const int n0 = blockIdx.x * 128;
  const int m0 = blockIdx.y * 128;
  f32x4 acc[4][4] = {};
  for (int k0 = 0; k0 < 256; k0 += 32) {
    __syncthreads();
    stage_tile(wo, 256, m0, k0, As, tid);
#pragma unroll
    for (int e = 0; e < 2; e++) {  // B: 128 n-rows x 32 c-cols, l-weighted combine
      int c = tid + e * 256;
      int row = c >> 2, seg = c & 3;
      int bs = n0 + row, cc = k0 + seg * 8;
      u16x8 t;
      if (nsplit == 1) {
        t = *(const u16x8*)(ao + ((size_t)bs << 8) + cc);
      } else {
        int b = bs >> 12, s = bs & 4095, head = cc >> 6;
        int li = (b * 4 + head) * Ss + s;
        float accv[8] = {0.f, 0.f, 0.f, 0.f, 0.f, 0.f, 0.f, 0.f};
        float lsum = 0.f;
        for (int spl = 0; spl < nsplit; spl++) {
          float l = lpart[(size_t)spl * (16 * Ss) + li];
          u16x8 a = *(const u16x8*)(AOP + (size_t)spl * ELEMS + ((size_t)bs << 8) + cc);
          lsum += l;
#pragma unroll
          for (int i = 0; i < 8; i++) accv[i] += l * bf2f(a[i]);
        }
        float inv = 1.0f / lsum;
#pragma unroll
        for (int i = 0; i < 8; i++) t[i] = f2bf(accv[i] * inv);
      }
      *(u16x8*)&Bs[row][seg * 8] = t;
    }
    __syncthreads();
    bf16x8 a[4], b[4];
#pragma unroll
    for (int mt = 0; mt < 4; mt++) a[mt] = ldfrag(&As[wm * 64 + mt * 16 + lr][quad * 8]);
#pragma unroll
    for (int nt = 0; nt < 4; nt++) b[nt] = ldfrag(&Bs[wn * 64 + nt * 16 + lr][quad * 8]);
#pragma unroll
    for (int mt = 0; mt < 4; mt++)
#pragma unroll
      for (int nt = 0; nt < 4; nt++)
        acc[mt][nt] = __builtin_amdgcn_mfma_f32_16x16x32_bf16(a[mt], b[nt], acc[mt][nt], 0, 0, 0);
  }
#pragma unroll
  for (int mt = 0; mt < 4; mt++)
#pragma unroll
    for (int rg = 0; rg < 4; rg++) {
      int c = m0 + wm * 64 + mt * 16 + quad * 4 + rg;
      float bc = bo[c];
#pragma unroll
      for (int nt = 0; nt < 4; nt++) {
        int col = n0 + wn * 64 + nt * 16 + lr;
        int b_ = col >> 12, s = col & 4095;
        y[((size_t)(b_ * Cc + c) << 12) + s] = acc[mt][nt][rg] + bc;
      }
    }
}

extern "C" void kernel_launch(void* const* d_in, const int* in_sizes, int n_in,
                              void* d_out, int out_size, void* d_ws, size_t ws_size,
                              hipStream_t stream) {
  const float* x = (const float*)d_in[0];
  const float* w_qkv = (const float*)d_in[1];
  const float* b_qkv = (const float*)d_in[2];
  const float* w_o = (const float*)d_in[3];
  const float* b_o = (const float*)d_in[4];
  float* y = (float*)d_out;
  u16* ws = (u16*)d_ws;
  u16* xt = ws;                        // [0, E) — reused as ao (nsplit==1 fallback)
  u16* q = ws + (size_t)ELEMS;
  u16* k = ws + (size_t)2 * ELEMS;
  u16* vt = ws + (size_t)3 * ELEMS;
  u16* ao = xt;
  u16* wqb = ws + (size_t)4 * ELEMS;   // 196608
  u16* wob = wqb + 196608;             // 65536
  const size_t Wu16 = (size_t)4 * ELEMS + 262144;
  // need(n) bytes = bf16 ws incl. n partial slabs, + n*16*Ss f32 for lpart
  auto need = [&](int n) { return (Wu16 + (size_t)n * ELEMS) * 2 + (size_t)n * 16 * Ss * 4; };
  const int nsplit = (ws_size >= need(4)) ? 4 : (ws_size >= need(2)) ? 2 : 1;
  u16* aop = ws + Wu16;                // nsplit*ELEMS u16 normalized partials
  u16* v = aop;                        // plain V aliases aop (dead before k_attn writes)
  float* lpart = (float*)(aop + (size_t)nsplit * ELEMS);

  k_transpose<<<dim3(64, 4, 4), 256, 0, stream>>>(x, xt, w_qkv, w_o, wqb, wob);
  k_qkv<<<dim3(128, 6), 256, 0, stream>>>(xt, wqb, b_qkv, q, k, v);
  k_vt<<<dim3(64, 16), 256, 0, stream>>>(v, vt);
  k_attn<<<dim3(16, 16, nsplit), 256, 0, stream>>>(q, k, vt, ao, aop, lpart, nsplit);
  k_oproj<<<dim3(128, 2), 256, 0, stream>>>(wob, ao, aop, lpart, b_o, y, nsplit);
}

// Round 4
// 179.458 us; speedup vs baseline: 3.6295x; 1.0522x over previous
//
#include <hip/hip_runtime.h>
#include <stdint.h>
#include <type_traits>

#define DI __device__ __forceinline__

typedef __attribute__((ext_vector_type(8))) __bf16 bf16x8;
typedef __attribute__((ext_vector_type(8))) unsigned short u16x8;
typedef __attribute__((ext_vector_type(4))) float f32x4;
typedef __attribute__((ext_vector_type(4))) uint32_t u32x4;
typedef unsigned short u16;

constexpr int Bb = 4, Cc = 256, Ss = 4096, HD = 64;
constexpr int ELEMS = Bb * Cc * Ss;  // 4194304

DI float bf2f(u16 h) { union { unsigned u; float f; } x; x.u = ((unsigned)h) << 16; return x.f; }
DI u16 f2bf(float f) {
  union { float f; unsigned u; } x; x.f = f;
  return (u16)((x.u + 0x7FFFu + ((x.u >> 16) & 1u)) >> 16);
}
DI uint32_t pack2bf_trunc(float a, float b) {  // low16=bf(a), high16=bf(b), truncating
  union { float f; uint32_t u; } xa, xb;
  xa.f = a; xb.f = b;
  return __builtin_amdgcn_perm(xb.u, xa.u, 0x07060302u);
}
DI bf16x8 ldfrag(const u16* p) { return __builtin_bit_cast(bf16x8, *(const u16x8*)p); }

// async global->LDS DMA, 16B per lane. LDS dest = wave-uniform base + lane*16 (linear);
// source address is per-lane (carries the swizzle).
DI void g2l16(const u16* g, u16* l) {
  __builtin_amdgcn_global_load_lds((const __attribute__((address_space(1))) uint32_t*)(const void*)g,
                                   (__attribute__((address_space(3))) uint32_t*)(void*)l, 16, 0, 0);
}

// ---------------- kernel 0: x (B,C,S) fp32 -> xt (B,S,C) bf16; + weight conversion fused ----------------
__global__ __launch_bounds__(256) void k_transpose(const float* __restrict__ x, u16* __restrict__ xt,
                                                   const float* __restrict__ wq, const float* __restrict__ wo,
                                                   u16* __restrict__ wqb, u16* __restrict__ wob) {
  __shared__ u16 T[64][72];
  const int st = blockIdx.x, ct = blockIdx.y, b = blockIdx.z;
  const int tid = threadIdx.x;
  // fused weight conversion: 1024 blocks x 256 threads == 262144 == 196608 + 65536
  {
    int flat = blockIdx.x + 64 * blockIdx.y + 256 * blockIdx.z;
    int widx = flat * 256 + tid;
    if (widx < 196608) wqb[widx] = f2bf(wq[widx]);
    else wob[widx - 196608] = f2bf(wo[widx - 196608]);
  }
#pragma unroll
  for (int e = 0; e < 2; e++) {
    int ss = tid + e * 256;
    int r = ss >> 3, seg = ss & 7;
    size_t base = ((size_t)(b * Cc + ct * 64 + r) << 12) + st * 64 + seg * 8;
    u16x8 t;
#pragma unroll
    for (int j = 0; j < 8; j++) t[j] = f2bf(x[base + j]);
    *(u16x8*)&T[r][(seg ^ ((r >> 3) & 7)) * 8] = t;
  }
  __syncthreads();
#pragma unroll
  for (int e = 0; e < 2; e++) {
    int ss = tid + e * 256;
    int sr = ss >> 3, cseg = ss & 7;
    u16x8 o;
#pragma unroll
    for (int j = 0; j < 8; j++) {
      int row = cseg * 8 + j;
      o[j] = T[row][(((sr >> 3) ^ cseg) * 8) + (sr & 7)];
    }
    *(u16x8*)(xt + ((size_t)(b * Ss + st * 64 + sr) << 8) + ct * 64 + cseg * 8) = o;
  }
}

// ---- shared GEMM staging: rows [r0,r0+128) x cols [k0,k0+32), pitch-40 LDS ----
DI void stage_tile(const u16* __restrict__ src, int pitch, int r0, int k0, u16 (*dst)[40], int tid) {
#pragma unroll
  for (int e = 0; e < 2; e++) {
    int c = tid + e * 256;
    int row = c >> 2, seg = c & 3;
    u16x8 t = *(const u16x8*)(src + (size_t)(r0 + row) * pitch + k0 + seg * 8);
    *(u16x8*)&dst[row][seg * 8] = t;
  }
}

// ---------------- kernel 1: qkv GEMM.  q:[bh][s][64]*(0.125*log2e)  k,v:[bh][s][64] ----------------
__global__ __launch_bounds__(256) void k_qkv(const u16* __restrict__ xt, const u16* __restrict__ w,
                                             const float* __restrict__ bias,
                                             u16* __restrict__ q, u16* __restrict__ kk_, u16* __restrict__ vv_) {
  __shared__ u16 As[128][40], Bs[128][40];
  const int tid = threadIdx.x;
  const int wv = tid >> 6, lane = tid & 63;
  const int wm = wv >> 1, wn = wv & 1;
  const int lr = lane & 15, quad = lane >> 4;
  const int r0 = blockIdx.x * 128;
  const int j0 = blockIdx.y * 128;
  f32x4 acc[4][4] = {};
  for (int k0 = 0; k0 < 256; k0 += 32) {
    __syncthreads();
    stage_tile(xt, 256, r0, k0, As, tid);
    stage_tile(w, 256, j0, k0, Bs, tid);
    __syncthreads();
    bf16x8 a[4], b[4];
#pragma unroll
    for (int mt = 0; mt < 4; mt++) a[mt] = ldfrag(&As[wm * 64 + mt * 16 + lr][quad * 8]);
#pragma unroll
    for (int nt = 0; nt < 4; nt++) b[nt] = ldfrag(&Bs[wn * 64 + nt * 16 + lr][quad * 8]);
#pragma unroll
    for (int mt = 0; mt < 4; mt++)
#pragma unroll
      for (int nt = 0; nt < 4; nt++)
        acc[mt][nt] = __builtin_amdgcn_mfma_f32_16x16x32_bf16(a[mt], b[nt], acc[mt][nt], 0, 0, 0);
  }
#pragma unroll
  for (int nt = 0; nt < 4; nt++) {
    int j = j0 + wn * 64 + nt * 16 + lr;
    float bj = bias[j];
    int part = j >> 8, cc = j & 255, head = cc >> 6, d = cc & 63;
    u16* outp = (part == 0) ? q : (part == 1) ? kk_ : vv_;
    float sc = (part == 0) ? 0.18033688f : 1.0f;  // 0.125*log2(e), exp2-domain scores
#pragma unroll
    for (int mt = 0; mt < 4; mt++)
#pragma unroll
      for (int rg = 0; rg < 4; rg++) {
        int row = r0 + wm * 64 + mt * 16 + quad * 4 + rg;
        int b_ = row >> 12, s = row & 4095;
        outp[((size_t)((b_ * 4 + head) * Ss + s) << 6) + d] = f2bf((acc[mt][nt][rg] + bj) * sc);
      }
  }
}

// ---------------- v [bh][s][64] -> vt [bh][d][chunk*64 + slot] (key-permuted transpose) ----------------
__global__ __launch_bounds__(256) void k_vt(const u16* __restrict__ v, u16* __restrict__ vt) {
  __shared__ u16 T[64][72];
  const int chunk = blockIdx.x, bh = blockIdx.y;
  const int tid = threadIdx.x;
#pragma unroll
  for (int e = 0; e < 2; e++) {
    int row = (tid >> 3) + e * 32, seg = tid & 7;
    *(u16x8*)&T[row][(seg ^ ((row >> 3) & 7)) * 8] =
        *(const u16x8*)(v + ((size_t)(bh * Ss + chunk * 64 + row) << 6) + seg * 8);
  }
  __syncthreads();
#pragma unroll
  for (int e = 0; e < 2; e++) {
    int d = (tid >> 3) + e * 32, seg = tid & 7;
    u16x8 o;
#pragma unroll
    for (int j = 0; j < 8; j++) {
      int slot = seg * 8 + j;
      int t = (((slot >> 5) & 1) << 1) | ((slot >> 2) & 1);
      int w6 = t * 16 + (((slot >> 3) & 3) << 2) + (slot & 3);
      o[j] = T[w6][(((d >> 3) ^ ((w6 >> 3) & 7)) * 8) + (d & 7)];
    }
    *(u16x8*)(vt + ((size_t)(bh * 64 + d) << 12) + chunk * 64 + seg * 8) = o;
  }
}

// ---------------- kernel 2: flash attention, S^T form, exp2 no-max softmax ----------------
// Cross-chunk software pipeline (T15): while chunk kc runs QK-MFMA + exp2 (VALU-dense),
// chunk kc-1's PV-MFMA issues in the same instruction stream (independent) — one wave now
// feeds both the MFMA and VALU pipes instead of alternating phases. P fragments for the
// previous chunk live in paA/paB (ping-pong by NAME — no runtime-indexed reg arrays).
// V is triple-buffered in LDS: stage writes V[(kc+1)%3], PV reads V[(kc-1)%3].
// K/V staged via global_load_lds DMA with pre-swizzled per-lane source (linear LDS dest).
__global__ __launch_bounds__(256, 2) void k_attn(const u16* __restrict__ Q, const u16* __restrict__ K,
                                                 const u16* __restrict__ VT, u16* __restrict__ AO,
                                                 u16* __restrict__ AOP, float* __restrict__ lpart,
                                                 int nsplit) {
  __shared__ u16 Kl[2][64][64];
  __shared__ u16 Vl[3][64][64];
  const int tid = threadIdx.x;
  const int wv = tid >> 6, lane = tid & 63;
  const int lr = lane & 15, quad = lane >> 4;
  const int bh = blockIdx.y;
  const int b_ = bh >> 2, head = bh & 3;
  const int qbase = blockIdx.x * 256 + wv * 64;
  const int sp = blockIdx.z;
  const int nchunk = 64 / nsplit, kcg0 = sp * nchunk;  // nchunk is even (32 or 64)
  const u16* Qh = Q + (size_t)bh * Ss * HD;
  const u16* Kh = K + (size_t)bh * Ss * HD;
  const u16* Vh = VT + (size_t)bh * HD * Ss;  // [d][perm(s)]

  bf16x8 qb[4][2];
#pragma unroll
  for (int nt = 0; nt < 4; nt++)
#pragma unroll
    for (int ks = 0; ks < 2; ks++)
      qb[nt][ks] = ldfrag(Qh + (size_t)(qbase + nt * 16 + lr) * HD + ks * 32 + quad * 8);

  u16x8 ov;
#pragma unroll
  for (int j = 0; j < 8; j++) ov[j] = 0x3F80;
  const bf16x8 ones = __builtin_bit_cast(bf16x8, ov);

  f32x4 O[4][4] = {};
  f32x4 lacc[4] = {};

  // DMA staging: wave wv covers rows wv*16..wv*16+15 of both 64x64 tiles.
  // per-lane source granule = (l&7) ^ (l>>3) implements the XOR swizzle at the source.
  const int lrow = lane >> 3;
  const int lseg = ((lane & 7) ^ lrow) * 8;
  const int kd0 = wv * 16 + lrow;
  const u16* pK0 = Kh + ((size_t)(kcg0 * 64 + kd0) << 6) + lseg;
  const u16* pK1 = pK0 + (8 << 6);
  const u16* pV0 = Vh + ((size_t)kd0 << 12) + kcg0 * 64 + lseg;
  const u16* pV1 = pV0 + ((size_t)8 << 12);
  auto stage = [&](int kb, int vbuf) {
    g2l16(pK0, &Kl[kb][wv * 16][0]);
    g2l16(pK1, &Kl[kb][wv * 16 + 8][0]);
    g2l16(pV0, &Vl[vbuf][wv * 16][0]);
    g2l16(pV1, &Vl[vbuf][wv * 16 + 8][0]);
    pK0 += 4096; pK1 += 4096; pV0 += 64; pV1 += 64;  // next chunk
  };

  // packed P fragments (exp2 output), pa[h][mt] is the MFMA A-operand for PV
  u32x4 paA[2][4], paB[2][4];

  auto pv_slice = [&](int t, u32x4 (&paR)[2][4], int vprev) {
    const int hp = t >> 1, dt0 = (t & 1) * 2;
#pragma unroll
    for (int dd = 0; dd < 2; dd++) {
      const int dt = dt0 + dd;
      bf16x8 vb = ldfrag(&Vl[vprev][dt * 16 + lr][((hp * 4 + quad) ^ (lr & 7)) * 8]);
      __builtin_amdgcn_s_setprio(1);
#pragma unroll
      for (int mt = 0; mt < 4; mt++)
        O[mt][dt] = __builtin_amdgcn_mfma_f32_16x16x32_bf16(
            __builtin_bit_cast(bf16x8, paR[hp][mt]), vb, O[mt][dt], 0, 0, 0);
      __builtin_amdgcn_s_setprio(0);
    }
    if (t & 1) {
#pragma unroll
      for (int mt = 0; mt < 4; mt++)
        lacc[mt] = __builtin_amdgcn_mfma_f32_16x16x32_bf16(
            __builtin_bit_cast(bf16x8, paR[hp][mt]), ones, lacc[mt], 0, 0, 0);
    }
  };

  auto body = [&](int kc, auto dopv, auto dostage, u32x4 (&paW)[2][4], u32x4 (&paR)[2][4]) {
    const int cur = kc & 1;
    const int vprev = (kc + 2) % 3;  // == (kc-1) mod 3
    if constexpr (decltype(dostage)::value) stage((kc + 1) & 1, (kc + 1) % 3);
#pragma unroll
    for (int t = 0; t < 4; t++) {
      // QK for 16-row kv tile t of chunk kc
      const int krow = t * 16 + lr;
      bf16x8 ka0 = ldfrag(&Kl[cur][krow][(quad ^ (lr & 7)) * 8]);
      bf16x8 ka1 = ldfrag(&Kl[cur][krow][((4 + quad) ^ (lr & 7)) * 8]);
      f32x4 St[4] = {};
      __builtin_amdgcn_s_setprio(1);
#pragma unroll
      for (int nt = 0; nt < 4; nt++)
        St[nt] = __builtin_amdgcn_mfma_f32_16x16x32_bf16(ka0, qb[nt][0], St[nt], 0, 0, 0);
#pragma unroll
      for (int nt = 0; nt < 4; nt++)
        St[nt] = __builtin_amdgcn_mfma_f32_16x16x32_bf16(ka1, qb[nt][1], St[nt], 0, 0, 0);
      __builtin_amdgcn_s_setprio(0);
      // PV slice t for chunk kc-1 — independent of St; hides St latency, feeds MFMA pipe
      // while exp2 below feeds VALU
      if constexpr (decltype(dopv)::value) pv_slice(t, paR, vprev);
      // exp2 + pack tile t -> paW
      const int h = t >> 1, k2 = (t & 1) * 2;
#pragma unroll
      for (int nt = 0; nt < 4; nt++) {
        float p0 = __builtin_amdgcn_exp2f(St[nt][0]);
        float p1 = __builtin_amdgcn_exp2f(St[nt][1]);
        float p2 = __builtin_amdgcn_exp2f(St[nt][2]);
        float p3 = __builtin_amdgcn_exp2f(St[nt][3]);
        paW[h][nt][k2] = pack2bf_trunc(p0, p1);
        paW[h][nt][k2 + 1] = pack2bf_trunc(p2, p3);
      }
    }
    __syncthreads();
  };

  using TT = std::bool_constant<true>;
  using FF = std::bool_constant<false>;

  stage(0, 0);
  __syncthreads();
  body(0, FF{}, TT{}, paA, paB);  // chunk 0: QK only
  int kc = 1;
  for (; kc + 2 < nchunk; kc += 2) {
    body(kc, TT{}, TT{}, paB, paA);
    body(kc + 1, TT{}, TT{}, paA, paB);
  }
  // kc == nchunk-1 (odd tail): last chunk, no stage
  body(nchunk - 1, TT{}, FF{}, paB, paA);
  // drain: PV for chunk nchunk-1
  {
    const int vlast = (nchunk - 1) % 3;
#pragma unroll
    for (int t = 0; t < 4; t++) pv_slice(t, paB, vlast);
  }

  // epilogue: normalize by this split's l, write bf16 (AO if nsplit==1, else partial slot sp)
  u16* dst = (nsplit == 1) ? AO : (AOP + (size_t)sp * ELEMS);
  if (nsplit > 1 && lr == 0) {
    float* lp = lpart + (size_t)sp * (16 * Ss) + bh * Ss;
#pragma unroll
    for (int mt = 0; mt < 4; mt++)
#pragma unroll
      for (int rg = 0; rg < 4; rg++) lp[qbase + mt * 16 + quad * 4 + rg] = lacc[mt][rg];
  }
#pragma unroll
  for (int mt = 0; mt < 4; mt++)
#pragma unroll
    for (int rg = 0; rg < 4; rg++) {
      float inv = 1.0f / lacc[mt][rg];
      int s = qbase + mt * 16 + quad * 4 + rg;
#pragma unroll
      for (int dt = 0; dt < 4; dt++)
        dst[((size_t)(b_ * Ss + s) << 8) + head * 64 + dt * 16 + lr] = f2bf(O[mt][dt][rg] * inv);
    }
}

// ---------------- kernel 3 (fused combine + oproj): y^T = w_o * combine(aop)^T + b_o ----------------
__global__ __launch_bounds__(256) void k_oproj(const u16* __restrict__ wo, const u16* __restrict__ ao,
                                               const u16* __restrict__ AOP, const float* __restrict__ lpart,
                                               const float* __restrict__ bo, float* __restrict__ y, int nsplit) {
  __shared__ u16 As[128][40], Bs[128][40];
  const int tid = threadIdx.x;
  const int wv = tid >> 6, lane = tid & 63;
  const int wm = wv >> 1, wn = wv & 1;
  const int lr = lane & 15, quad = lane >> 4;
  const int n0 = blockIdx.x * 128;
  const int m0 = blockIdx.y * 128;
  f32x4 acc[4][4] = {};
  for (int k0 = 0; k0 < 256; k0 += 32) {
    __syncthreads();
    stage_tile(wo, 256, m0, k0, As, tid);
#pragma unroll
    for (int e = 0; e < 2; e++) {  // B: 128 n-rows x 32 c-cols, l-weighted combine
      int c = tid + e * 256;
      int row = c >> 2, seg = c & 3;
      int bs = n0 + row, cc = k0 + seg * 8;
      u16x8 t;
      if (nsplit == 1) {
        t = *(const u16x8*)(ao + ((size_t)bs << 8) + cc);
      } else {
        int b = bs >> 12, s = bs & 4095, head = cc >> 6;
        int li = (b * 4 + head) * Ss + s;
        float accv[8] = {0.f, 0.f, 0.f, 0.f, 0.f, 0.f, 0.f, 0.f};
        float lsum = 0.f;
        for (int spl = 0; spl < nsplit; spl++) {
          float l = lpart[(size_t)spl * (16 * Ss) + li];
          u16x8 a = *(const u16x8*)(AOP + (size_t)spl * ELEMS + ((size_t)bs << 8) + cc);
          lsum += l;
#pragma unroll
          for (int i = 0; i < 8; i++) accv[i] += l * bf2f(a[i]);
        }
        float inv = 1.0f / lsum;
#pragma unroll
        for (int i = 0; i < 8; i++) t[i] = f2bf(accv[i] * inv);
      }
      *(u16x8*)&Bs[row][seg * 8] = t;
    }
    __syncthreads();
    bf16x8 a[4], b[4];
#pragma unroll
    for (int mt = 0; mt < 4; mt++) a[mt] = ldfrag(&As[wm * 64 + mt * 16 + lr][quad * 8]);
#pragma unroll
    for (int nt = 0; nt < 4; nt++) b[nt] = ldfrag(&Bs[wn * 64 + nt * 16 + lr][quad * 8]);
#pragma unroll
    for (int mt = 0; mt < 4; mt++)
#pragma unroll
      for (int nt = 0; nt < 4; nt++)
        acc[mt][nt] = __builtin_amdgcn_mfma_f32_16x16x32_bf16(a[mt], b[nt], acc[mt][nt], 0, 0, 0);
  }
#pragma unroll
  for (int mt = 0; mt < 4; mt++)
#pragma unroll
    for (int rg = 0; rg < 4; rg++) {
      int c = m0 + wm * 64 + mt * 16 + quad * 4 + rg;
      float bc = bo[c];
#pragma unroll
      for (int nt = 0; nt < 4; nt++) {
        int col = n0 + wn * 64 + nt * 16 + lr;
        int b_ = col >> 12, s = col & 4095;
        y[((size_t)(b_ * Cc + c) << 12) + s] = acc[mt][nt][rg] + bc;
      }
    }
}

extern "C" void kernel_launch(void* const* d_in, const int* in_sizes, int n_in,
                              void* d_out, int out_size, void* d_ws, size_t ws_size,
                              hipStream_t stream) {
  const float* x = (const float*)d_in[0];
  const float* w_qkv = (const float*)d_in[1];
  const float* b_qkv = (const float*)d_in[2];
  const float* w_o = (const float*)d_in[3];
  const float* b_o = (const float*)d_in[4];
  float* y = (float*)d_out;
  u16* ws = (u16*)d_ws;
  u16* xt = ws;                        // [0, E) — reused as ao (nsplit==1 fallback)
  u16* q = ws + (size_t)ELEMS;
  u16* k = ws + (size_t)2 * ELEMS;
  u16* vt = ws + (size_t)3 * ELEMS;
  u16* ao = xt;
  u16* wqb = ws + (size_t)4 * ELEMS;   // 196608
  u16* wob = wqb + 196608;             // 65536
  const size_t Wu16 = (size_t)4 * ELEMS + 262144;
  // need(n) bytes = bf16 ws incl. n partial slabs, + n*16*Ss f32 for lpart
  auto need = [&](int n) { return (Wu16 + (size_t)n * ELEMS) * 2 + (size_t)n * 16 * Ss * 4; };
  const int nsplit = (ws_size >= need(2)) ? 2 : 1;  // nsplit=2: 512 blocks fills 2 blocks/CU (reg limit); 4 only added combine cost
  u16* aop = ws + Wu16;                // nsplit*ELEMS u16 normalized partials
  u16* v = aop;                        // plain V aliases aop (dead before k_attn writes)
  float* lpart = (float*)(aop + (size_t)nsplit * ELEMS);

  k_transpose<<<dim3(64, 4, 4), 256, 0, stream>>>(x, xt, w_qkv, w_o, wqb, wob);
  k_qkv<<<dim3(128, 6), 256, 0, stream>>>(xt, wqb, b_qkv, q, k, v);
  k_vt<<<dim3(64, 16), 256, 0, stream>>>(v, vt);
  k_attn<<<dim3(16, 16, nsplit), 256, 0, stream>>>(q, k, vt, ao, aop, lpart, nsplit);
  k_oproj<<<dim3(128, 2), 256, 0, stream>>>(wob, ao, aop, lpart, b_o, y, nsplit);
}